// Round 14
// baseline (413.044 us; speedup 1.0000x reference)
//
#include <hip/hip_runtime.h>

// Problem constants (match reference setup_inputs)
constexpr int  Bc    = 8;
constexpr int  Nc    = 2048;
constexpr int  DIN   = 5;
constexpr int  DHID  = 32;
constexpr int  NROWS = Bc * Nc;                   // 16384
constexpr long NF4   = (long)NROWS * (Nc / 4);    // 8,388,608 float4 groups

typedef float vf4 __attribute__((ext_vector_type(4)));

// ---------------------------------------------------------------------------
// PROBE A / A3: pure float4 read stream, 16 fully-unrolled independent loads
// per thread, one atomicAdd per wave at the end (keeps loads live).
// ---------------------------------------------------------------------------
__global__ __launch_bounds__(256) void probe_read(
    const float* __restrict__ src, float* __restrict__ dummy)
{
    const long tid0   = (long)blockIdx.x * 256 + threadIdx.x;
    const long stride = (long)gridDim.x * 256;    // 524288
    float p0 = 0.f, p1 = 0.f, p2 = 0.f, p3 = 0.f;
    #pragma unroll
    for (int it = 0; it < 16; ++it) {
        const long f = tid0 + (long)it * stride;
        const float4 g = *reinterpret_cast<const float4*>(src + (f << 2));
        p0 += g.x; p1 += g.y; p2 += g.z; p3 += g.w;
    }
    float p = (p0 + p1) + (p2 + p3);
    #pragma unroll
    for (int off = 32; off > 0; off >>= 1) p += __shfl_xor(p, off, 64);
    if ((threadIdx.x & 63) == 0) atomicAdd(&dummy[blockIdx.x & 1023], p);
}

// ---------------------------------------------------------------------------
// PROBE A2: blocked read — each thread owns 4 consecutive float4 (64 B),
// 4 outer iterations. Tests whether per-thread batching deepens the pipeline.
// ---------------------------------------------------------------------------
__global__ __launch_bounds__(256) void probe_read4(
    const float* __restrict__ src, float* __restrict__ dummy)
{
    const long t  = (long)blockIdx.x * 256 + threadIdx.x;
    const long nt = (long)gridDim.x * 256;
    float p0 = 0.f, p1 = 0.f, p2 = 0.f, p3 = 0.f;
    #pragma unroll
    for (int it = 0; it < 4; ++it) {
        const long base = (t + (long)it * nt) * 4;   // float4 index
        #pragma unroll
        for (int k = 0; k < 4; ++k) {
            const float4 g = *reinterpret_cast<const float4*>(src + ((base + k) << 2));
            p0 += g.x; p1 += g.y; p2 += g.z; p3 += g.w;
        }
    }
    float p = (p0 + p1) + (p2 + p3);
    #pragma unroll
    for (int off = 32; off > 0; off >>= 1) p += __shfl_xor(p, off, 64);
    if ((threadIdx.x & 63) == 0) atomicAdd(&dummy[blockIdx.x & 1023], p);
}

// ---------------------------------------------------------------------------
// PROBE B: read+write copy stream (G -> out, NT store).
// ---------------------------------------------------------------------------
__global__ __launch_bounds__(256) void probe_copy(
    const float* __restrict__ src, float* __restrict__ dst)
{
    const long tid0   = (long)blockIdx.x * 256 + threadIdx.x;
    const long stride = (long)gridDim.x * 256;
    #pragma unroll
    for (int it = 0; it < 16; ++it) {
        const long f = tid0 + (long)it * stride;
        const float4 g = *reinterpret_cast<const float4*>(src + (f << 2));
        vf4 o; o.x = g.x * 0.5f; o.y = g.y * 0.5f; o.z = g.z * 0.5f; o.w = g.w * 0.5f;
        __builtin_nontemporal_store(o, reinterpret_cast<vf4*>(dst + (f << 2)));
    }
}

// ---------------------------------------------------------------------------
// PROBE C: G-read + 5 u-streams + compute (pass1 body), single end atomic.
// Measures interference of the 5:1 cache-stream mix vs probe_read.
// ---------------------------------------------------------------------------
__global__ __launch_bounds__(256) void probe_read_u(
    const float* __restrict__ s, const float* __restrict__ G,
    const float* __restrict__ u, float* __restrict__ dummy, long gbs)
{
    const long tid0   = (long)blockIdx.x * 256 + threadIdx.x;
    const long stride = (long)gridDim.x * 256;
    float acc = 0.f;
    for (int it = 0; it < 16; ++it) {
        const long f = tid0 + (long)it * stride;
        const int r  = (int)(f >> 9);
        const int b  = r >> 11;
        const int i  = r & (Nc - 1);
        const int j0 = ((int)f & 511) * 4;
        const float4 g4 = *reinterpret_cast<const float4*>(
            G + (size_t)b * gbs + (size_t)i * Nc + j0);
        const float* sp = s + (size_t)r * DIN;
        const float* ub = u + (size_t)b * DIN * Nc;
        float vx = 0.f, vy = 0.f, vz = 0.f, vw = 0.f;
        #pragma unroll
        for (int d = 0; d < DIN; ++d) {
            const float sd = sp[d];
            const float4 u4 = *reinterpret_cast<const float4*>(ub + (size_t)d * Nc + j0);
            vx = fmaf(sd, u4.x, vx);
            vy = fmaf(sd, u4.y, vy);
            vz = fmaf(sd, u4.z, vz);
            vw = fmaf(sd, u4.w, vw);
        }
        acc += vx * vx * g4.x + vy * vy * g4.y + vz * vz * g4.z + vw * vw * g4.w;
    }
    #pragma unroll
    for (int off = 32; off > 0; off >>= 1) acc += __shfl_xor(acc, off, 64);
    if ((threadIdx.x & 63) == 0) atomicAdd(&dummy[blockIdx.x & 1023], acc);
}

// ---------------------------------------------------------------------------
// u[b, d, j] = sum_e M[d][e] * s[b, j, e],  M = Qw @ Kw^T (5x5)
// ---------------------------------------------------------------------------
__global__ __launch_bounds__(256) void u_precompute(
    const float* __restrict__ s, const float* __restrict__ Qw,
    const float* __restrict__ Kw, float* __restrict__ u)
{
    __shared__ float Msh[DIN * DIN];
    const int tid = threadIdx.x;
    if (tid < DIN * DIN) {
        const int d = tid / DIN, e = tid % DIN;
        float acc = 0.f;
        #pragma unroll
        for (int m = 0; m < DHID; ++m)
            acc = fmaf(Qw[d * DHID + m], Kw[e * DHID + m], acc);
        Msh[tid] = acc;
    }
    __syncthreads();
    const int g = blockIdx.x * 256 + tid;
    if (g >= NROWS) return;
    const int b = g >> 11;
    const int j = g & (Nc - 1);
    float sv[DIN];
    #pragma unroll
    for (int e = 0; e < DIN; ++e) sv[e] = s[(size_t)g * DIN + e];
    #pragma unroll
    for (int d = 0; d < DIN; ++d) {
        float acc = 0.f;
        #pragma unroll
        for (int e = 0; e < DIN; ++e) acc = fmaf(Msh[d * DIN + e], sv[e], acc);
        u[((size_t)b * DIN + d) * Nc + j] = acc;
    }
}

// ---------------------------------------------------------------------------
// Correctness carrier: R6's att_rows4 (best so far, 81 µs, passed).
// ---------------------------------------------------------------------------
__global__ __launch_bounds__(256, 4) void att_rows4(
    const float* __restrict__ s, const float* __restrict__ G,
    const float* __restrict__ u, float* __restrict__ out, long gbs)
{
    const int tid  = threadIdx.x;
    const int row0 = blockIdx.x * 4;
    const int b    = row0 >> 11;
    const int i0   = row0 & (Nc - 1);

    float si[4][DIN];
    #pragma unroll
    for (int r = 0; r < 4; ++r)
        #pragma unroll
        for (int d = 0; d < DIN; ++d)
            si[r][d] = s[(size_t)(row0 + r) * DIN + d];

    const float* ub = u + (size_t)b * DIN * Nc;
    const float* gB = G + (size_t)b * gbs;

    float a[4][2][4];
    float psum[4];
    #pragma unroll
    for (int r = 0; r < 4; ++r) psum[r] = 0.f;

    #pragma unroll
    for (int c = 0; c < 2; ++c) {
        const int j0 = c * 1024 + tid * 4;
        float4 ud[DIN];
        #pragma unroll
        for (int d = 0; d < DIN; ++d)
            ud[d] = *reinterpret_cast<const float4*>(ub + (size_t)d * Nc + j0);
        #pragma unroll
        for (int r = 0; r < 4; ++r) {
            const float4 g4 = *reinterpret_cast<const float4*>(
                gB + (size_t)(i0 + r) * Nc + j0);
            float vx = 0.f, vy = 0.f, vz = 0.f, vw = 0.f;
            #pragma unroll
            for (int d = 0; d < DIN; ++d) {
                vx = fmaf(si[r][d], ud[d].x, vx);
                vy = fmaf(si[r][d], ud[d].y, vy);
                vz = fmaf(si[r][d], ud[d].z, vz);
                vw = fmaf(si[r][d], ud[d].w, vw);
            }
            a[r][c][0] = vx * vx * g4.x;
            a[r][c][1] = vy * vy * g4.y;
            a[r][c][2] = vz * vz * g4.z;
            a[r][c][3] = vw * vw * g4.w;
            psum[r] += (a[r][c][0] + a[r][c][1]) + (a[r][c][2] + a[r][c][3]);
        }
    }

    #pragma unroll
    for (int r = 0; r < 4; ++r)
        #pragma unroll
        for (int off = 32; off > 0; off >>= 1)
            psum[r] += __shfl_xor(psum[r], off, 64);

    __shared__ float wpart[4][4];
    if ((tid & 63) == 0) {
        #pragma unroll
        for (int r = 0; r < 4; ++r) wpart[tid >> 6][r] = psum[r];
    }
    __syncthreads();

    float inv[4];
    #pragma unroll
    for (int r = 0; r < 4; ++r)
        inv[r] = 1.0f / ((wpart[0][r] + wpart[1][r]) +
                         (wpart[2][r] + wpart[3][r]) + 0.001f);

    #pragma unroll
    for (int c = 0; c < 2; ++c) {
        const int j0 = c * 1024 + tid * 4;
        #pragma unroll
        for (int r = 0; r < 4; ++r) {
            vf4 o;
            o.x = a[r][c][0] * inv[r];
            o.y = a[r][c][1] * inv[r];
            o.z = a[r][c][2] * inv[r];
            o.w = a[r][c][3] * inv[r];
            __builtin_nontemporal_store(
                o, reinterpret_cast<vf4*>(out + (size_t)(row0 + r) * Nc + j0));
        }
    }
}

// ---------------------------------------------------------------------------
// Fallback (no workspace): single-row blocks, M computed per block.
// ---------------------------------------------------------------------------
__global__ __launch_bounds__(256) void att_row_direct(
    const float* __restrict__ s, const float* __restrict__ G,
    const float* __restrict__ Qw, const float* __restrict__ Kw,
    float* __restrict__ out, long gbs)
{
    __shared__ float Msh[DIN * DIN];
    __shared__ float wpart[4];
    const int tid = threadIdx.x;
    if (tid < DIN * DIN) {
        const int d = tid / DIN, e = tid % DIN;
        float acc = 0.f;
        #pragma unroll
        for (int m = 0; m < DHID; ++m)
            acc = fmaf(Qw[d * DHID + m], Kw[e * DHID + m], acc);
        Msh[tid] = acc;
    }
    __syncthreads();

    const int row = blockIdx.x;
    const int b   = row >> 11;
    const int i   = row & (Nc - 1);

    float w[DIN];
    {
        float si[DIN];
        #pragma unroll
        for (int e = 0; e < DIN; ++e) si[e] = s[(size_t)row * DIN + e];
        #pragma unroll
        for (int d = 0; d < DIN; ++d) {
            float acc = 0.f;
            #pragma unroll
            for (int e = 0; e < DIN; ++e) acc = fmaf(si[e], Msh[e * DIN + d], acc);
            w[d] = acc;
        }
    }

    const float* gRow = G + (size_t)b * gbs + (size_t)i * Nc;
    const float* sb   = s + (size_t)b * Nc * DIN;
    float*       oRow = out + (size_t)row * Nc;

    float a[2][4];
    float lsum = 0.f;
    #pragma unroll
    for (int it = 0; it < 2; ++it) {
        const int j0 = it * 1024 + tid * 4;
        const float4 g4 = *reinterpret_cast<const float4*>(gRow + j0);
        float v[4];
        #pragma unroll
        for (int c = 0; c < 4; ++c) {
            const float* sj = sb + (size_t)(j0 + c) * DIN;
            float acc = 0.f;
            #pragma unroll
            for (int d = 0; d < DIN; ++d) acc = fmaf(w[d], sj[d], acc);
            v[c] = acc;
        }
        a[it][0] = v[0] * v[0] * g4.x;
        a[it][1] = v[1] * v[1] * g4.y;
        a[it][2] = v[2] * v[2] * g4.z;
        a[it][3] = v[3] * v[3] * g4.w;
        lsum += (a[it][0] + a[it][1]) + (a[it][2] + a[it][3]);
    }

    #pragma unroll
    for (int off = 32; off > 0; off >>= 1)
        lsum += __shfl_xor(lsum, off, 64);
    if ((tid & 63) == 0) wpart[tid >> 6] = lsum;
    __syncthreads();
    const float total = (wpart[0] + wpart[1]) + (wpart[2] + wpart[3]);
    const float inv = 1.0f / (total + 0.001f);

    #pragma unroll
    for (int it = 0; it < 2; ++it) {
        const int j0 = it * 1024 + tid * 4;
        vf4 o;
        o.x = a[it][0] * inv;
        o.y = a[it][1] * inv;
        o.z = a[it][2] * inv;
        o.w = a[it][3] * inv;
        __builtin_nontemporal_store(o, reinterpret_cast<vf4*>(oRow + j0));
    }
}

extern "C" void kernel_launch(void* const* d_in, const int* in_sizes, int n_in,
                              void* d_out, int out_size, void* d_ws, size_t ws_size,
                              hipStream_t stream)
{
    const float* s  = (const float*)d_in[0];
    const float* G  = (const float*)d_in[1];
    const float* Qw = (const float*)d_in[2];
    const float* Kw = (const float*)d_in[3];
    float* out = (float*)d_out;

    const long gbs = (in_sizes[1] == Nc * Nc) ? 0L : (long)Nc * Nc;

    // ws layout: dummy[1024] | u[B*DIN*N]
    const size_t needBytes = (size_t)(1024 + Bc * DIN * Nc) * sizeof(float);

    if (ws_size >= needBytes) {
        float* dummy = (float*)d_ws;
        float* u     = dummy + 1024;

        u_precompute<<<(NROWS + 255) / 256, 256, 0, stream>>>(s, Qw, Kw, u);

        // --- diagnostic probes (outputs dead; correctness from att_rows4) ---
        probe_read <<<2048, 256, 0, stream>>>(G, dummy);              // A : G-read ceiling
        probe_read4<<<2048, 256, 0, stream>>>(G, dummy);              // A2: blocked read
        probe_read <<<2048, 256, 0, stream>>>((const float*)d_out, dummy); // A3: out-alloc read
        probe_copy <<<2048, 256, 0, stream>>>(G, out);                // B : read+write stream
        probe_read_u<<<2048, 256, 0, stream>>>(s, G, u, dummy, gbs);  // C : G + 5 u-streams

        // --- real computation (overwrites out) ---
        att_rows4<<<NROWS / 4, 256, 0, stream>>>(s, G, u, out, gbs);
    } else {
        att_row_direct<<<NROWS, 256, 0, stream>>>(s, G, Qw, Kw, out, gbs);
    }
}